// Round 9
// baseline (427.572 us; speedup 1.0000x reference)
//
#include <hip/hip_runtime.h>

// Problem constants (fixed by the reference): B=4, S=2048, D=DK=1024.
constexpr int Bc  = 4;
constexpr int Sc  = 2048;
constexpr int Dc  = 1024;
constexpr int DKc = 1024;
constexpr long BSc = (long)Bc * Sc;      // 8192 flattened rows of x

typedef __attribute__((ext_vector_type(8))) __bf16 bf16x8;
typedef __attribute__((ext_vector_type(4))) float  floatx4;

__device__ inline __bf16 f2bf(float f) {
  unsigned u = __builtin_bit_cast(unsigned, f);
  u = (u + 0x7FFFu + ((u >> 16) & 1u)) >> 16;      // RNE
  unsigned short s = (unsigned short)u;
  return __builtin_bit_cast(__bf16, s);
}
__device__ inline float bf2f(__bf16 h) {
  unsigned u = ((unsigned)__builtin_bit_cast(unsigned short, h)) << 16;
  return __builtin_bit_cast(float, u);
}

// async global->LDS, 16B per lane. lds base must be wave-uniform; HW scatters
// lane i's 16B to ldsbase + i*16.
__device__ inline void stage16(const __bf16* g, __bf16* l) {
  __builtin_amdgcn_global_load_lds(
      (const __attribute__((address_space(1))) unsigned int*)g,
      (__attribute__((address_space(3))) unsigned int*)l, 16, 0, 0);
}

// ---------------------------------------------------------------------------
// prep: fp32->bf16 hi/lo splits for x (32768 blks), WQ (4096), WK (4096),
// plus WV transpose (hi only; 1024 blks). One dispatch (round-7).
// ---------------------------------------------------------------------------
__global__ __launch_bounds__(256) void prep(
    const float* __restrict__ x,  __bf16* __restrict__ xhi, __bf16* __restrict__ xlo,
    const float* __restrict__ wq, __bf16* __restrict__ qhi, __bf16* __restrict__ qlo,
    const float* __restrict__ wk, __bf16* __restrict__ khi, __bf16* __restrict__ klo,
    const float* __restrict__ wv, __bf16* __restrict__ vthi) {
  __shared__ float tile[32][33];
  long blk = blockIdx.x;
  if (blk >= 40960) {                 // WV transpose: Wt[dk][d] = W[d][dk]
    int t   = (int)(blk - 40960);
    int bx  = t & 31, by = t >> 5;
    int thx = threadIdx.x & 31, thy = threadIdx.x >> 5;   // 32 x 8
    int xI  = bx * 32 + thx, yI = by * 32 + thy;
#pragma unroll
    for (int j = 0; j < 32; j += 8)
      tile[thy + j][thx] = wv[(long)(yI + j) * DKc + xI];
    __syncthreads();
    int xO = by * 32 + thx, yO = bx * 32 + thy;
#pragma unroll
    for (int j = 0; j < 32; j += 8)
      vthi[(long)(yO + j) * Dc + xO] = f2bf(tile[thx][thy + j]);
    return;
  }
  const float* in; __bf16 *hi, *lo; long base;
  if (blk < 32768)      { in = x;  hi = xhi; lo = xlo; base = blk * 256; }
  else if (blk < 36864) { in = wq; hi = qhi; lo = qlo; base = (blk - 32768) * 256; }
  else                  { in = wk; hi = khi; lo = klo; base = (blk - 36864) * 256; }
  long i = base + threadIdx.x;
  float f = in[i];
  __bf16 h = f2bf(f);
  hi[i] = h;
  lo[i] = f2bf(f - bf2f(h));
}

// ---------------------------------------------------------------------------
// Shared m97-structure NT MFMA GEMM body. 128x128 tile, 4 waves 2x2, each
// 64x64 (4x4 accs of 16x16x32). BK=32 via global_load_lds width=16 with the
// XOR chunk swizzle on the global source (round-3: conflicts 8.4M -> 0).
// One kernel per mode (round-8: fused wrappers merged register budgets).
//
// MODE_QK: split (3 MFMA), bf16 hi+lo store via LDS round-trip.
// MODE_V : plain, TRANSPOSED store via padded LDS (stride 136; round-8).
// MODE_S : split; epilogue computes per-column tile max M_t, stores
//          p = exp(s - M_t) bf16 + Pmax/Psum partials (round-6).
// MODE_PV: plain async-staged GEMM on rescaled P (round-9: ffac application
//          moved to a standalone rescale pass; manual staging removed).
// ---------------------------------------------------------------------------
enum { MODE_QK = 0, MODE_V = 1, MODE_S = 2, MODE_PV = 3 };
constexpr int VSTR = 136;   // padded stride for the V transpose epilogue

template <int MODE>
__device__ __forceinline__ void gemm_body(
    char* smem,
    const __bf16* __restrict__ Ahi, const __bf16* __restrict__ Alo,
    const __bf16* __restrict__ Bhi, const __bf16* __restrict__ Blo,
    float* __restrict__ Cf, __bf16* __restrict__ Chi, __bf16* __restrict__ Clo,
    float* __restrict__ Pmax, float* __restrict__ Psum, float scale) {
  constexpr bool SPLIT = (MODE == MODE_QK || MODE == MODE_S);
  constexpr int  K = (MODE == MODE_PV) ? Sc : Dc;
  constexpr int  N = (MODE == MODE_S) ? Sc : DKc;
  constexpr long aBatch = (MODE == MODE_S) ? (long)Sc * DKc
                        : (MODE == MODE_PV) ? (long)Sc * Sc : 0;
  constexpr long bBatch = (MODE == MODE_S) ? (long)Sc * DKc
                        : (MODE == MODE_PV) ? (long)DKc * Sc : 0;
  constexpr long cBatch = (MODE == MODE_S) ? (long)Sc * Sc
                        : (MODE == MODE_PV) ? (long)Sc * DKc : 0;
  __bf16* sAh = (__bf16*)smem;           // [128][32] (chunk-swizzled)
  __bf16* sBh = sAh + 128 * 32;
  __bf16* sAl = sBh + 128 * 32;          // split only
  __bf16* sBl = sAl + 128 * 32;

  const int b    = blockIdx.z;
  const int wave = threadIdx.x >> 6;
  const int lane = threadIdx.x & 63;
  const int wm   = wave >> 1;            // 0..1
  const int wn   = wave & 1;             // 0..1
  const int m0   = blockIdx.y * 128;
  const int n0   = blockIdx.x * 128;

  const __bf16* Ab  = Ahi + (long)b * aBatch + (long)m0 * K;
  const __bf16* Bb  = Bhi + (long)b * bBatch + (long)n0 * K;
  const __bf16* Abl = SPLIT ? Alo + (long)b * aBatch + (long)m0 * K : nullptr;
  const __bf16* Bbl = SPLIT ? Blo + (long)b * bBatch + (long)n0 * K : nullptr;

  // Async staging: wave w stages rows [w*32,w*32+32); lane (r,c) loads global
  // chunk c^((r>>1)&3) -> physical LDS slot base + lane*16B.
  const int sr   = lane >> 2;                       // 0..15
  const int sc_  = lane & 3;                        // 0..3
  const int scol = (sc_ ^ ((sr >> 1) & 3)) * 8;     // swizzled global col

  floatx4 acc[4][4];
  const floatx4 zero = {0.f, 0.f, 0.f, 0.f};
#pragma unroll
  for (int i = 0; i < 4; ++i)
#pragma unroll
    for (int j = 0; j < 4; ++j) acc[i][j] = zero;

  const int frow = lane & 15;
  // Fragment read: logical chunk = lane>>4; physical chunk is XOR'd by row.
  const int pko = ((lane >> 4) ^ ((frow >> 1) & 3)) * 8;

#pragma unroll 1
  for (int k0 = 0; k0 < K; k0 += 32) {
#pragma unroll
    for (int i = 0; i < 2; ++i) {
      const int rb = wave * 32 + i * 16;            // wave-uniform row base
      const long go = (long)(rb + sr) * K + k0 + scol;
      stage16(Ab + go, sAh + rb * 32);
      stage16(Bb + go, sBh + rb * 32);
      if constexpr (SPLIT) {
        stage16(Abl + go, sAl + rb * 32);
        stage16(Bbl + go, sBl + rb * 32);
      }
    }
    __syncthreads();

    bf16x8 af[4], bfr[4], afl[4], bfl[4];
#pragma unroll
    for (int t = 0; t < 4; ++t) {
      af[t]  = *(const bf16x8*)(sAh + (wm * 64 + t * 16 + frow) * 32 + pko);
      bfr[t] = *(const bf16x8*)(sBh + (wn * 64 + t * 16 + frow) * 32 + pko);
      if constexpr (SPLIT) {
        afl[t] = *(const bf16x8*)(sAl + (wm * 64 + t * 16 + frow) * 32 + pko);
        bfl[t] = *(const bf16x8*)(sBl + (wn * 64 + t * 16 + frow) * 32 + pko);
      }
    }
#pragma unroll
    for (int mt = 0; mt < 4; ++mt)
#pragma unroll
      for (int nt = 0; nt < 4; ++nt) {
        acc[mt][nt] = __builtin_amdgcn_mfma_f32_16x16x32_bf16(af[mt], bfr[nt], acc[mt][nt], 0, 0, 0);
        if constexpr (SPLIT) {
          acc[mt][nt] = __builtin_amdgcn_mfma_f32_16x16x32_bf16(af[mt], bfl[nt], acc[mt][nt], 0, 0, 0);
          acc[mt][nt] = __builtin_amdgcn_mfma_f32_16x16x32_bf16(afl[mt], bfr[nt], acc[mt][nt], 0, 0, 0);
        }
      }
    __syncthreads();
  }

  // Epilogue. D layout: col=lane&15, row=(lane>>4)*4+reg (m89/m91-verified).
  const int crow0 = (lane >> 4) * 4;
  const int ccol  = lane & 15;
  const int tid   = threadIdx.x;

  if constexpr (MODE == MODE_QK) {
    __bf16* sT = (__bf16*)smem;          // [128][128] bf16 = 32KB
#pragma unroll 1
    for (int pass = 0; pass < 2; ++pass) {
      __syncthreads();
#pragma unroll
      for (int nt = 0; nt < 4; ++nt) {
        int col = wn * 64 + nt * 16 + ccol;
#pragma unroll
        for (int mt = 0; mt < 4; ++mt) {
          int row = wm * 64 + mt * 16 + crow0;
#pragma unroll
          for (int r = 0; r < 4; ++r) {
            float v = acc[mt][nt][r] * scale;
            __bf16 h = f2bf(v);
            sT[(row + r) * 128 + col] = pass ? f2bf(v - bf2f(h)) : h;
          }
        }
      }
      __syncthreads();
      __bf16* dst = pass ? Clo : Chi;
#pragma unroll
      for (int c = 0; c < 8; ++c) {
        int flat = c * 2048 + tid * 8;
        int row = flat >> 7, col = flat & 127;
        *(bf16x8*)(dst + (long)(m0 + row) * N + n0 + col) = *(const bf16x8*)(sT + flat);
      }
    }
    return;
  }

  if constexpr (MODE == MODE_V) {
    // Transpose via LDS, padded stride VSTR=136 (272B = 17x16B: rows stay
    // 16B-aligned; bank advance 4/row -> 2-way aliasing, free per m136).
    __bf16* sT = (__bf16*)smem;          // [128][VSTR]
#pragma unroll
    for (int nt = 0; nt < 4; ++nt) {
      int nl = wn * 64 + nt * 16 + ccol;
#pragma unroll
      for (int mt = 0; mt < 4; ++mt) {
        int ml = wm * 64 + mt * 16 + crow0;
#pragma unroll
        for (int r = 0; r < 4; ++r)
          sT[(long)nl * VSTR + ml + r] = f2bf(acc[mt][nt][r]);
      }
    }
    __syncthreads();
    const int bb   = m0 >> 11;          // tile fully within one batch
    const int seq0 = m0 & (Sc - 1);
    __bf16* dst = Chi + (long)bb * DKc * Sc + seq0;
#pragma unroll
    for (int c = 0; c < 8; ++c) {
      int flat = c * 2048 + tid * 8;    // logical 128x128; 16B per thread
      int row = flat >> 7, col = flat & 127;
      *(bf16x8*)(dst + (long)(n0 + row) * Sc + col) =
          *(const bf16x8*)(sT + (long)row * VSTR + col);
    }
    return;
  }

  if constexpr (MODE == MODE_S) {
    // (1) per-column tile max over 128 rows.
    float cm[4];
#pragma unroll
    for (int nt = 0; nt < 4; ++nt) {
      float mx = -3.0e38f;
#pragma unroll
      for (int mt = 0; mt < 4; ++mt)
#pragma unroll
        for (int r = 0; r < 4; ++r) mx = fmaxf(mx, acc[mt][nt][r] * scale);
      cm[nt] = mx;
    }
#pragma unroll
    for (int off = 16; off <= 32; off <<= 1)
#pragma unroll
      for (int nt = 0; nt < 4; ++nt)
        cm[nt] = fmaxf(cm[nt], __shfl_xor(cm[nt], off, 64));
    float* smax = (float*)smem;          // [2][128]
    float* ssum = smax + 256;
    if (lane < 16)
#pragma unroll
      for (int nt = 0; nt < 4; ++nt)
        smax[wm * 128 + wn * 64 + nt * 16 + lane] = cm[nt];
    __syncthreads();
    float mfin[4];
#pragma unroll
    for (int nt = 0; nt < 4; ++nt) {
      int c = wn * 64 + nt * 16 + ccol;
      mfin[nt] = fmaxf(smax[c], smax[128 + c]);
    }
    // (2) column expsum vs tile max.
    float ps[4];
#pragma unroll
    for (int nt = 0; nt < 4; ++nt) {
      float s = 0.f;
#pragma unroll
      for (int mt = 0; mt < 4; ++mt)
#pragma unroll
        for (int r = 0; r < 4; ++r)
          s += __expf(acc[mt][nt][r] * scale - mfin[nt]);
      ps[nt] = s;
    }
#pragma unroll
    for (int off = 16; off <= 32; off <<= 1)
#pragma unroll
      for (int nt = 0; nt < 4; ++nt) ps[nt] += __shfl_xor(ps[nt], off, 64);
    if (lane < 16)
#pragma unroll
      for (int nt = 0; nt < 4; ++nt)
        ssum[wm * 128 + wn * 64 + nt * 16 + lane] = ps[nt];
    __syncthreads();
    if (tid < 128) {
      long o = ((long)b * 16 + blockIdx.y) * Sc + n0 + tid;
      Pmax[o] = fmaxf(smax[tid], smax[128 + tid]);
      Psum[o] = ssum[tid] + ssum[128 + tid];
    }
    __syncthreads();                     // smax/ssum dead; reuse as sT
    // (3) p = exp(s - M_t) -> bf16, LDS round-trip, coalesced store.
    __bf16* sT = (__bf16*)smem;
#pragma unroll
    for (int nt = 0; nt < 4; ++nt) {
      int col = wn * 64 + nt * 16 + ccol;
#pragma unroll
      for (int mt = 0; mt < 4; ++mt) {
        int row = wm * 64 + mt * 16 + crow0;
#pragma unroll
        for (int r = 0; r < 4; ++r)
          sT[(row + r) * 128 + col] =
              f2bf(__expf(acc[mt][nt][r] * scale - mfin[nt]));
      }
    }
    __syncthreads();
#pragma unroll
    for (int c = 0; c < 8; ++c) {
      int flat = c * 2048 + tid * 8;
      int row = flat >> 7, col = flat & 127;
      *(bf16x8*)(Chi + (long)b * cBatch + (long)(m0 + row) * N + n0 + col) =
          *(const bf16x8*)(sT + flat);
    }
    return;
  }

  // MODE_PV: direct fp32 store.
#pragma unroll
  for (int nt = 0; nt < 4; ++nt) {
    int cn = n0 + wn * 64 + nt * 16 + ccol;
#pragma unroll
    for (int mt = 0; mt < 4; ++mt) {
#pragma unroll
      for (int r = 0; r < 4; ++r) {
        int cm_ = m0 + wm * 64 + mt * 16 + crow0 + r;
        Cf[(long)b * cBatch + (long)cm_ * N + cn] = acc[mt][nt][r] * scale;
      }
    }
  }
}

// ---------------------------------------------------------------------------
// Wrappers — one kernel per mode (separate register budgets).
// ---------------------------------------------------------------------------
__global__ __launch_bounds__(256) void gemm_t(
    const __bf16* __restrict__ xhi, const __bf16* __restrict__ xlo,
    const __bf16* __restrict__ gthi, const __bf16* __restrict__ gtlo,
    __bf16* __restrict__ thi, __bf16* __restrict__ tlo) {
  __shared__ __align__(16) char smem[32768];
  gemm_body<MODE_QK>(smem, xhi, xlo, gthi, gtlo, nullptr, thi, tlo,
                     nullptr, nullptr, 1.0f);
}

__global__ __launch_bounds__(256) void gemm_v(
    const __bf16* __restrict__ xhi, const __bf16* __restrict__ wvthi,
    __bf16* __restrict__ vt) {
  __shared__ __align__(16) char smem[128 * VSTR * 2];   // 34 KB (epilogue)
  gemm_body<MODE_V>(smem, xhi, nullptr, wvthi, nullptr, nullptr, vt, nullptr,
                    nullptr, nullptr, 1.0f);
}

__global__ __launch_bounds__(256) void gemm_s(
    const __bf16* __restrict__ thi, const __bf16* __restrict__ tlo,
    const __bf16* __restrict__ xhi, const __bf16* __restrict__ xlo,
    __bf16* __restrict__ P, float* __restrict__ Pmax, float* __restrict__ Psum) {
  __shared__ __align__(16) char smem[32768];
  gemm_body<MODE_S>(smem, thi, tlo, xhi, xlo, nullptr, P, nullptr,
                    Pmax, Psum, 0.03125f);
}

__global__ __launch_bounds__(256) void gemm_pv(
    const __bf16* __restrict__ P, const __bf16* __restrict__ vt,
    float* __restrict__ out) {
  __shared__ __align__(16) char smem[16384];
  gemm_body<MODE_PV>(smem, P, nullptr, vt, nullptr, out, nullptr, nullptr,
                     nullptr, nullptr, 1.0f);
}

// ---------------------------------------------------------------------------
// G GEMM, 64x64 tiles (256 blocks; round-7). Gt[m][n] = sum_k WK[m,k]WQ[n,k],
// split operands (3 MFMA), hi/lo output.
// ---------------------------------------------------------------------------
__global__ __launch_bounds__(256) void gemm_g64(
    const __bf16* __restrict__ Ahi, const __bf16* __restrict__ Alo,
    const __bf16* __restrict__ Bhi, const __bf16* __restrict__ Blo,
    __bf16* __restrict__ Chi, __bf16* __restrict__ Clo) {
  constexpr int K = Dc, N = DKc;
  __shared__ __align__(16) char smem[16384];
  __bf16* sAh = (__bf16*)smem;           // [64][32]
  __bf16* sBh = sAh + 64 * 32;
  __bf16* sAl = sBh + 64 * 32;
  __bf16* sBl = sAl + 64 * 32;

  const int wave = threadIdx.x >> 6;
  const int lane = threadIdx.x & 63;
  const int wm   = wave >> 1, wn = wave & 1;
  const int m0   = blockIdx.y * 64;
  const int n0   = blockIdx.x * 64;

  const int sr   = lane >> 2;
  const int sc_  = lane & 3;
  const int scol = (sc_ ^ ((sr >> 1) & 3)) * 8;
  const int frow = lane & 15;
  const int pko  = ((lane >> 4) ^ ((frow >> 1) & 3)) * 8;

  floatx4 acc[2][2];
  const floatx4 zero = {0.f, 0.f, 0.f, 0.f};
#pragma unroll
  for (int i = 0; i < 2; ++i)
#pragma unroll
    for (int j = 0; j < 2; ++j) acc[i][j] = zero;

#pragma unroll 1
  for (int k0 = 0; k0 < K; k0 += 32) {
    const int rb = wave * 16;                       // wave stages 16 rows
    const long ga = (long)(m0 + rb + sr) * K + k0 + scol;
    const long gb = (long)(n0 + rb + sr) * K + k0 + scol;
    stage16(Ahi + ga, sAh + rb * 32);
    stage16(Alo + ga, sAl + rb * 32);
    stage16(Bhi + gb, sBh + rb * 32);
    stage16(Blo + gb, sBl + rb * 32);
    __syncthreads();

    bf16x8 af[2], bfr[2], afl[2], bfl[2];
#pragma unroll
    for (int t = 0; t < 2; ++t) {
      af[t]  = *(const bf16x8*)(sAh + (wm * 32 + t * 16 + frow) * 32 + pko);
      bfr[t] = *(const bf16x8*)(sBh + (wn * 32 + t * 16 + frow) * 32 + pko);
      afl[t] = *(const bf16x8*)(sAl + (wm * 32 + t * 16 + frow) * 32 + pko);
      bfl[t] = *(const bf16x8*)(sBl + (wn * 32 + t * 16 + frow) * 32 + pko);
    }
#pragma unroll
    for (int mt = 0; mt < 2; ++mt)
#pragma unroll
      for (int nt = 0; nt < 2; ++nt) {
        acc[mt][nt] = __builtin_amdgcn_mfma_f32_16x16x32_bf16(af[mt], bfr[nt], acc[mt][nt], 0, 0, 0);
        acc[mt][nt] = __builtin_amdgcn_mfma_f32_16x16x32_bf16(af[mt], bfl[nt], acc[mt][nt], 0, 0, 0);
        acc[mt][nt] = __builtin_amdgcn_mfma_f32_16x16x32_bf16(afl[mt], bfr[nt], acc[mt][nt], 0, 0, 0);
      }
    __syncthreads();
  }

  const int crow0 = (lane >> 4) * 4;
  const int ccol  = lane & 15;
  const int tid   = threadIdx.x;
  __bf16* sT = (__bf16*)smem;            // [64][64] = 8KB
#pragma unroll 1
  for (int pass = 0; pass < 2; ++pass) {
    __syncthreads();
#pragma unroll
    for (int nt = 0; nt < 2; ++nt) {
      int col = wn * 32 + nt * 16 + ccol;
#pragma unroll
      for (int mt = 0; mt < 2; ++mt) {
        int row = wm * 32 + mt * 16 + crow0;
#pragma unroll
        for (int r = 0; r < 4; ++r) {
          float v = acc[mt][nt][r];
          __bf16 h = f2bf(v);
          sT[(row + r) * 64 + col] = pass ? f2bf(v - bf2f(h)) : h;
        }
      }
    }
    __syncthreads();
    __bf16* dst = pass ? Clo : Chi;
#pragma unroll
    for (int c = 0; c < 2; ++c) {
      int flat = c * 2048 + tid * 8;
      int row = flat >> 6, col = flat & 63;
      *(bf16x8*)(dst + (long)(m0 + row) * N + n0 + col) = *(const bf16x8*)(sT + flat);
    }
  }
}

// ---------------------------------------------------------------------------
// Fold 16 q-tile partials -> ffac[b][t][k] = exp(M_t - M_k) / Z_k.
// ---------------------------------------------------------------------------
__global__ __launch_bounds__(256) void softmax_reduce(const float* __restrict__ Pmax,
                                                      const float* __restrict__ Psum,
                                                      float* __restrict__ Ffac) {
  int idx = blockIdx.x * 256 + threadIdx.x;   // b*2048 + k
  int b = idx >> 11, k = idx & (Sc - 1);
  const float* pm = Pmax + (long)b * 16 * Sc + k;
  const float* ps = Psum + (long)b * 16 * Sc + k;
  float M = -3.0e38f;
#pragma unroll
  for (int t = 0; t < 16; ++t) M = fmaxf(M, pm[(long)t * Sc]);
  float S = 0.f;
#pragma unroll
  for (int t = 0; t < 16; ++t)
    S += ps[(long)t * Sc] * __expf(pm[(long)t * Sc] - M);
  float inv = 1.0f / S;
  float* fo = Ffac + (long)b * 16 * Sc + k;
#pragma unroll
  for (int t = 0; t < 16; ++t)
    fo[(long)t * Sc] = __expf(pm[(long)t * Sc] - M) * inv;
}

// ---------------------------------------------------------------------------
// In-place rescale: P[b][q][k] *= ffac[b][q>>7][k]. One block per row;
// thread handles 8 consecutive k (bf16x8 + 2 float4 loads, fully coalesced).
// Bit-identical to the former fused apply (same bf2f*fp32 -> f2bf sequence).
// ---------------------------------------------------------------------------
__global__ __launch_bounds__(256) void rescale_p(__bf16* __restrict__ P,
                                                 const float* __restrict__ Ffac) {
  long row = blockIdx.x;                 // b*2048 + q
  int b = (int)(row >> 11), q = (int)(row & (Sc - 1));
  const float* f = Ffac + ((long)b * 16 + (q >> 7)) * Sc;
  __bf16* p = P + (row << 11);
  int k0 = threadIdx.x * 8;
  bf16x8 v = *(const bf16x8*)(p + k0);
  bf16x8 o;
#pragma unroll
  for (int j = 0; j < 8; ++j) o[j] = f2bf(bf2f(v[j]) * f[k0 + j]);
  *(bf16x8*)(p + k0) = o;
}

// ---------------------------------------------------------------------------
extern "C" void kernel_launch(void* const* d_in, const int* in_sizes, int n_in,
                              void* d_out, int out_size, void* d_ws, size_t ws_size,
                              hipStream_t stream) {
  const float* x  = (const float*)d_in[0];
  const float* WQ = (const float*)d_in[1];
  const float* WK = (const float*)d_in[2];
  const float* WV = (const float*)d_in[3];
  float* out = (float*)d_out;
  char* ws = (char*)d_ws;
  const long MB = 1024L * 1024L;

  // Workspace layout (peak ~131 MB).
  __bf16* xhi  = (__bf16*)(ws + 0 * MB);     // 16 MB
  __bf16* xlo  = (__bf16*)(ws + 16 * MB);    // 16 MB
  __bf16* wqhi = (__bf16*)(ws + 32 * MB);    // 2 MB each (element-wise split)
  __bf16* wqlo = (__bf16*)(ws + 34 * MB);
  __bf16* wkhi = (__bf16*)(ws + 36 * MB);
  __bf16* wklo = (__bf16*)(ws + 38 * MB);
  __bf16* wvthi= (__bf16*)(ws + 40 * MB);    // transposed, hi only
  __bf16* gthi = (__bf16*)(ws + 44 * MB);    // 2 MB each: Gt = (WQ WK^T)^T
  __bf16* gtlo = (__bf16*)(ws + 46 * MB);
  __bf16* thi  = (__bf16*)(ws + 48 * MB);    // 16 MB each: T = x*G
  __bf16* tlo  = (__bf16*)(ws + 64 * MB);
  __bf16* vt   = (__bf16*)(ws + 80 * MB);    // 16 MB, [B][DK][S]
  __bf16* P    = (__bf16*)(ws + 96 * MB);    // 32 MB, p = exp(s - M_t), bf16
  float*  pmax = (float*)(ws + 128 * MB);    // 512 KB, [B][16][S]
  float*  psum = (float*)(ws + 129 * MB);    // 512 KB
  float*  ffac = (float*)(ws + 130 * MB);    // 512 KB, [B][16][S]

  // 1. casts + WV transpose (one dispatch)
  prep<<<41984, 256, 0, stream>>>(x, xhi, xlo, WQ, wqhi, wqlo, WK, wkhi, wklo,
                                  WV, wvthi);

  // 2. Gt[d][a] = G[a][d]: NT(A=WK, B=WQ), 64x64 tiles -> 256 blocks.
  gemm_g64<<<dim3(16, 16), 256, 0, stream>>>(wkhi, wklo, wqhi, wqlo, gthi, gtlo);

  // 3. T = x*G (split).
  gemm_t<<<dim3(DKc / 128, BSc / 128, 1), 256, 0, stream>>>(
      xhi, xlo, gthi, gtlo, thi, tlo);

  // 4. Vt = (x*WV)^T per batch (plain).
  gemm_v<<<dim3(DKc / 128, BSc / 128, 1), 256, 0, stream>>>(xhi, wvthi, vt);

  // 5. S = T*x^T * scale; emits p (bf16) + per-tile column max/expsum.
  gemm_s<<<dim3(Sc / 128, Sc / 128, Bc), 256, 0, stream>>>(
      thi, tlo, xhi, xlo, P, pmax, psum);

  // 6. partials -> ffac
  softmax_reduce<<<32, 256, 0, stream>>>(pmax, psum, ffac);

  // 7. P *= ffac (in place; attn finalized)
  rescale_p<<<(int)BSc, 256, 0, stream>>>(P, ffac);

  // 8. out = attn @ Vt^T (plain async m97 GEMM).
  gemm_pv<<<dim3(DKc / 128, Sc / 128, Bc), 256, 0, stream>>>(P, vt, out);
}